// Round 5
// baseline (82.455 us; speedup 1.0000x reference)
//
#include <hip/hip_runtime.h>
#include <hip/hip_bf16.h>
#include <math.h>

#define LRELU_ALPHA 0.2f

typedef __attribute__((ext_vector_type(8))) short bf16x8;
typedef __attribute__((ext_vector_type(4))) float f32x4;

__device__ __forceinline__ unsigned short f2bf(float f) {
    union { float f; unsigned u; } v; v.f = f;
    unsigned r = v.u + 0x7fffu + ((v.u >> 16) & 1u);
    return (unsigned short)(r >> 16);
}
__device__ __forceinline__ float bfbits(unsigned s) {
    union { unsigned u; float f; } v; v.u = s << 16;
    return v.f;
}

// Kernel 0 (prep): Wt[h][n][k] = bf16(W[h][k][n]) for n<64;
// n=64+q: bf16(sum_o W[h][k][o]*a_q[o]), a_q = {ap[:64], ap[64:], an[:64], an[64:]}.
// Tail blocks: edge_out = ee @ et.
__global__ void prep_kernel(const float* __restrict__ W,
                            const float* __restrict__ a_pos, const float* __restrict__ a_neg,
                            const float* __restrict__ ee, const float* __restrict__ et,
                            unsigned short* __restrict__ Wt, float* __restrict__ edge_out,
                            int H, int ET) {
    const int WTE = H * 80 * 64;
    int t = blockIdx.x * blockDim.x + threadIdx.x;
    if (t < WTE) {
        int k = t & 63, n = (t >> 6) % 80, h = t / (80 * 64);
        float v;
        if (n < 64) {
            v = W[(size_t)h * 4096 + k * 64 + n];
        } else {
            int q = n - 64;
            const float* a  = (q < 2 ? a_pos : a_neg) + (size_t)h * 128 + (q & 1) * 64;
            const float* wr = W + (size_t)h * 4096 + k * 64;
            v = 0.f;
            for (int o = 0; o < 64; ++o) v = fmaf(wr[o], a[o], v);
        }
        Wt[t] = f2bf(v);
    } else {
        int s = t - WTE;
        if (s < ET * 64) {
            int e = s >> 6, o = s & 63;
            float acc = 0.f;
#pragma unroll
            for (int k = 0; k < 64; ++k)
                acc = fmaf(ee[e * 64 + k], et[k * 64 + o], acc);
            edge_out[s] = acc;
        }
    }
}

// Kernel 1: MFMA with SWAPPED operands: D = Wt_tile x embed^T, so each lane holds
// 16 dims of ONE row u (4 contiguous 4-runs) -> ushort4 stores. Score tile (nt=4)
// lands whole in grp==0 lanes -> 2 float2 stores (split dst/src).
__global__ __launch_bounds__(256) void wh_mfma_kernel(
    const float* __restrict__ nf, const unsigned short* __restrict__ Wt,
    const int* __restrict__ unique_nodes,
    unsigned short* __restrict__ WhB, float2* __restrict__ sc_dst,
    float2* __restrict__ sc_src, int U, int H)
{
    const int wave = threadIdx.x >> 6;
    const int lane = threadIdx.x & 63;
    const int grp  = lane >> 4;   // k block
    const int r    = lane & 15;   // u-local (output col after swap)
    const long u0  = ((long)blockIdx.x * 4 + wave) * 16;
    if (u0 >= U) return;

    const long u  = u0 + r;
    const long ur = (u < U) ? u : (long)(U - 1);
    const float* erow = nf + (size_t)unique_nodes[ur] * 64 + grp * 8;
    const float4 e0 = *(const float4*)(erow);
    const float4 e1 = *(const float4*)(erow + 4);
    const float4 e2 = *(const float4*)(erow + 32);
    const float4 e3 = *(const float4*)(erow + 36);
    bf16x8 a0, a1;
    a0[0] = (short)f2bf(e0.x); a0[1] = (short)f2bf(e0.y);
    a0[2] = (short)f2bf(e0.z); a0[3] = (short)f2bf(e0.w);
    a0[4] = (short)f2bf(e1.x); a0[5] = (short)f2bf(e1.y);
    a0[6] = (short)f2bf(e1.z); a0[7] = (short)f2bf(e1.w);
    a1[0] = (short)f2bf(e2.x); a1[1] = (short)f2bf(e2.y);
    a1[2] = (short)f2bf(e2.z); a1[3] = (short)f2bf(e2.w);
    a1[4] = (short)f2bf(e3.x); a1[5] = (short)f2bf(e3.y);
    a1[6] = (short)f2bf(e3.z); a1[7] = (short)f2bf(e3.w);

    for (int h = 0; h < H; ++h) {
        f32x4 acc[5];
#pragma unroll
        for (int nt = 0; nt < 5; ++nt) {
            acc[nt] = (f32x4)(0.f);
            const unsigned short* wp = Wt + (((size_t)h * 80 + nt * 16 + r) * 64 + grp * 8);
            bf16x8 b0 = *(const bf16x8*)wp;        // same lane->k map as A frags
            bf16x8 b1 = *(const bf16x8*)(wp + 32);
            // swapped: A = Wt frag, B = embed frag  =>  D[n_w][u]
            acc[nt] = __builtin_amdgcn_mfma_f32_16x16x32_bf16(b0, a0, acc[nt], 0, 0, 0);
            acc[nt] = __builtin_amdgcn_mfma_f32_16x16x32_bf16(b1, a1, acc[nt], 0, 0, 0);
        }
        if (u < U) {
            // lane holds dims n_w = nt*16 + grp*4 + j of row u
            unsigned short* wrow = WhB + ((size_t)h * U + u) * 64 + grp * 4;
#pragma unroll
            for (int nt = 0; nt < 4; ++nt) {
                ushort4 pk;
                pk.x = f2bf(acc[nt][0]); pk.y = f2bf(acc[nt][1]);
                pk.z = f2bf(acc[nt][2]); pk.w = f2bf(acc[nt][3]);
                *(ushort4*)(wrow + nt * 16) = pk;
            }
            if (grp == 0) {   // score tile: q = j  ({pd, ps, nd, ns})
                sc_dst[(size_t)h * U + u] = make_float2(acc[4][0], acc[4][2]);
                sc_src[(size_t)h * U + u] = make_float2(acc[4][1], acc[4][3]);
            }
        }
    }
}

// Kernel 2: one wave per (row, head), head pinned to XCD pair {2h, 2h+1}.
// Gather: readlane-broadcast col -> wave-uniform row base (SALU addressing),
// lane = dim, all 33 rows loaded into registers BEFORE softmax (latency overlap).
template <int DP, int DN>
__global__ __launch_bounds__(256) void agg_kernel(
    const int* __restrict__ row_unique,
    const int* __restrict__ pos_col, const int* __restrict__ neg_col,
    const unsigned short* __restrict__ WhB, const float2* __restrict__ sc_dst,
    const float2* __restrict__ sc_src,
    float* __restrict__ out, int N, int U, int rDP, int rDN, int H, int pinned)
{
    const int DEGP = DP > 0 ? DP : rDP;
    const int DEGN = DN > 0 ? DN : rDN;
    const int NE   = DEGP + 1 + DEGN;       // 33

    const int wave = threadIdx.x >> 6;
    const int lane = threadIdx.x & 63;

    int i, h;
    if (pinned) {
        const int xcd = blockIdx.x & 7;
        h = xcd >> 1;
        const int rg = ((blockIdx.x >> 3) << 1) | (blockIdx.x & 1);
        i = rg * 4 + wave;
    } else {
        const long j = (long)blockIdx.x * 4 + wave;
        i = (int)(j % N);
        h = (int)(j / N);
        if (h >= H) return;
    }
    if (i >= N) return;

    const float2 sd = sc_dst[(size_t)h * U + row_unique[i]];   // {pos_dst, neg_dst}

    int col = 0;
    float score = -INFINITY;
    if (lane < NE) {
        if (lane < DEGP)       col = pos_col[(size_t)i * DEGP + lane];
        else if (lane == DEGP) col = pos_col[(size_t)N * DEGP + i];  // self edge
        else                   col = neg_col[(size_t)i * DEGN + (lane - DEGP - 1)];
        const float2 ss = sc_src[(size_t)h * U + col];               // {pos_src, neg_src}
        const float raw = (lane <= DEGP) ? (sd.x + ss.x) : (sd.y + ss.y);
        score = (raw > 0.f) ? raw : LRELU_ALPHA * raw;
    }

    const unsigned short* whb = WhB + (size_t)h * U * 64;

    if constexpr (DP > 0) {
        constexpr int CNE = DP + 1 + DN;
        // issue all gathers first (need only col) — softmax below hides their latency
        unsigned vv[CNE];
#pragma unroll
        for (int e = 0; e < CNE; ++e) {
            const int ce = __builtin_amdgcn_readlane(col, e);   // wave-uniform
            vv[e] = whb[(size_t)(unsigned)ce * 64 + lane];
        }
        float m = score;
#pragma unroll
        for (int off = 32; off; off >>= 1) m = fmaxf(m, __shfl_xor(m, off, 64));
        const float ex = (lane < CNE) ? __expf(score - m) : 0.f;
        float ssum = ex;
#pragma unroll
        for (int off = 32; off; off >>= 1) ssum += __shfl_xor(ssum, off, 64);
        const float att = ex / ssum;

        float acc0 = 0.f, acc1 = 0.f;
#pragma unroll
        for (int e = 0; e < CNE; ++e) {
            const float ae = __int_as_float(
                __builtin_amdgcn_readlane(__float_as_int(att), e));
            const float w = bfbits(vv[e]);
            if (e & 1) acc1 = fmaf(ae, w, acc1);
            else       acc0 = fmaf(ae, w, acc0);
        }
        out[(size_t)i * (H * 64) + h * 64 + lane] = fmaxf(acc0 + acc1, 0.f);
    } else {
        float m = score;
#pragma unroll
        for (int off = 32; off; off >>= 1) m = fmaxf(m, __shfl_xor(m, off, 64));
        const float ex = (lane < NE) ? __expf(score - m) : 0.f;
        float ssum = ex;
#pragma unroll
        for (int off = 32; off; off >>= 1) ssum += __shfl_xor(ssum, off, 64);
        const float att = ex / ssum;

        float acc = 0.f;
        for (int e = 0; e < NE; ++e) {
            const int   ce = __shfl(col, e, 64);
            const float ae = __shfl(att, e, 64);
            acc = fmaf(ae, bfbits(whb[(size_t)(unsigned)ce * 64 + lane]), acc);
        }
        out[(size_t)i * (H * 64) + h * 64 + lane] = fmaxf(acc, 0.f);
    }
}

extern "C" void kernel_launch(void* const* d_in, const int* in_sizes, int n_in,
                              void* d_out, int out_size, void* d_ws, size_t ws_size,
                              hipStream_t stream) {
    const float* nf     = (const float*)d_in[0];
    const float* W      = (const float*)d_in[1];
    const float* a_pos  = (const float*)d_in[2];
    const float* a_neg  = (const float*)d_in[3];
    const float* ee     = (const float*)d_in[4];
    const float* et     = (const float*)d_in[5];
    const int* unique_nodes = (const int*)d_in[6];
    const int* row_unique   = (const int*)d_in[7];
    const int* pos_col  = (const int*)d_in[9];
    const int* neg_col  = (const int*)d_in[11];

    const int U    = in_sizes[6];
    const int N    = in_sizes[7];
    const int Epos = in_sizes[8];
    const int Eneg = in_sizes[10];
    const int H    = in_sizes[1] / (64 * 64);   // W is [H,64,64]
    const int DEGN = Eneg / N;                  // 16
    const int DEGP = Epos / N - 1;              // 16 (self edges appended)
    const int ET   = in_sizes[4] / 64;          // 32 edge types

    unsigned short* WhB = (unsigned short*)d_ws;
    const size_t whBytes = (((size_t)H * U * 64 * sizeof(unsigned short)) + 255) & ~(size_t)255;
    float2* sc_dst = (float2*)((char*)d_ws + whBytes);
    const size_t sdBytes = (((size_t)H * U * sizeof(float2)) + 255) & ~(size_t)255;
    float2* sc_src = (float2*)((char*)d_ws + whBytes + sdBytes);
    const size_t ssBytes = sdBytes;
    unsigned short* Wt = (unsigned short*)((char*)d_ws + whBytes + sdBytes + ssBytes);
    float* out = (float*)d_out;

    const int PT = H * 80 * 64 + ET * 64;
    prep_kernel<<<(PT + 255) / 256, 256, 0, stream>>>(W, a_pos, a_neg, ee, et, Wt,
                                                      out + (size_t)N * H * 64, H, ET);

    const int nwaves = (U + 15) / 16;
    wh_mfma_kernel<<<(nwaves + 3) / 4, 256, 0, stream>>>(nf, Wt, unique_nodes, WhB,
                                                         sc_dst, sc_src, U, H);

    const long NBp = (long)N * H / 4;
    const int pinned = (H == 4 && (N % 4) == 0 && (NBp % 8) == 0) ? 1 : 0;
    const long NB = pinned ? NBp : ((long)N * H + 3) / 4;
    if (DEGP == 16 && DEGN == 16)
        agg_kernel<16, 16><<<NB, 256, 0, stream>>>(row_unique, pos_col, neg_col, WhB,
                                                   sc_dst, sc_src, out, N, U, DEGP, DEGN, H, pinned);
    else
        agg_kernel<0, 0><<<NB, 256, 0, stream>>>(row_unique, pos_col, neg_col, WhB,
                                                 sc_dst, sc_src, out, N, U, DEGP, DEGN, H, pinned);
}